// Round 3
// baseline (462.476 us; speedup 1.0000x reference)
//
#include <hip/hip_runtime.h>
#include <hip/hip_bf16.h>

typedef unsigned short ushort_t;
typedef __attribute__((ext_vector_type(8))) short short8;
typedef __attribute__((ext_vector_type(4))) float f32x4;
typedef __attribute__((ext_vector_type(4))) unsigned short us4;

#define B_SZ 8192
#define D_FT 784
#define K_PAD 832   // 13 * 64
#define N_KT 13
#define THRESH 0.9f

#define GLOBAL_AS(p) ((const __attribute__((address_space(1))) void*)(p))
#define LDS_AS(p)    ((__attribute__((address_space(3))) void*)(p))

__device__ inline unsigned short f2bf(float f) {
    unsigned int u = __float_as_uint(f);
    unsigned int r = (u + 0x7fffu + ((u >> 16) & 1u)) >> 16;
    return (unsigned short)r;
}

// Wave-per-row preproc: 2048 blocks x 4 waves; wave w handles row blockIdx*4+w.
// conv 2x2/s2 + bias -> 4x4 unitary per patch-group -> qf (LDS), row norm ->
// qn bf16 (padded to 832), logits + log_softmax.
__global__ __launch_bounds__(256) void preproc_kernel(
    const float* __restrict__ x, const float* __restrict__ conv_w,
    const float* __restrict__ conv_b, const float* __restrict__ unitary,
    const float* __restrict__ lin_w, const float* __restrict__ lin_b,
    float* __restrict__ log_probs, ushort_t* __restrict__ qn)
{
    __shared__ float xr[4][784];
    __shared__ float qf[4][784];

    const int t = threadIdx.x, lane = t & 63, wave = t >> 6;
    const int b = blockIdx.x * 4 + wave;
    float* xw = xr[wave];
    float* qw = qf[wave];

    // stage x row (196 float4 per wave)
    const float4* xsrc = (const float4*)(x + (size_t)b * 784);
    #pragma unroll
    for (int i = lane; i < 196; i += 64) ((float4*)xw)[i] = xsrc[i];
    __syncthreads();

    float sumsq = 0.f;
    for (int g = lane; g < 196; g += 64) {
        const int c = g / 49, p = g % 49;
        const float w00 = conv_w[c*4+0], w01 = conv_w[c*4+1];
        const float w10 = conv_w[c*4+2], w11 = conv_w[c*4+3];
        const float bcv = conv_b[c];
        float feat[4];
        #pragma unroll
        for (int j = 0; j < 4; ++j) {
            const int s = 4*p + j;
            const int h = s / 14, wq = s % 14;
            const float* px = &xw[(2*h)*28 + 2*wq];
            feat[j] = bcv + w00*px[0] + w01*px[1] + w10*px[28] + w11*px[29];
        }
        #pragma unroll
        for (int w = 0; w < 4; ++w) {
            float v = unitary[w*4+0]*feat[0] + unitary[w*4+1]*feat[1]
                    + unitary[w*4+2]*feat[2] + unitary[w*4+3]*feat[3];
            qw[4*g + w] = v;
            sumsq += v * v;
        }
    }
    __syncthreads();

    // wave butterfly: all lanes get the row sum
    #pragma unroll
    for (int off = 1; off < 64; off <<= 1) sumsq += __shfl_xor(sumsq, off, 64);
    const float inv = 1.0f / (sqrtf(sumsq) + 1e-12f);

    // qn write: 208 x ushort4 (= 832 elems), zero-padded past 784
    ushort_t* qrow = qn + (size_t)b * K_PAD;
    for (int i = lane; i < 208; i += 64) {
        us4 o;
        if (i < 196) {
            #pragma unroll
            for (int j = 0; j < 4; ++j) o[j] = f2bf(qw[4*i + j] * inv);
        } else {
            o = (us4)0;
        }
        *(us4*)(qrow + 4*i) = o;
    }

    // logits: 10 dots of length 784, intra-wave
    float acc[10];
    #pragma unroll
    for (int cl = 0; cl < 10; ++cl) acc[cl] = 0.f;
    for (int k = lane; k < 784; k += 64) {
        const float v = qw[k];
        #pragma unroll
        for (int cl = 0; cl < 10; ++cl) acc[cl] += v * lin_w[cl*784 + k];
    }
    #pragma unroll
    for (int cl = 0; cl < 10; ++cl) {
        #pragma unroll
        for (int off = 1; off < 64; off <<= 1)
            acc[cl] += __shfl_xor(acc[cl], off, 64);
        acc[cl] += lin_b[cl];
    }
    if (lane == 0) {
        float mx = -1e30f;
        #pragma unroll
        for (int cl = 0; cl < 10; ++cl) mx = fmaxf(mx, acc[cl]);
        float se = 0.f;
        #pragma unroll
        for (int cl = 0; cl < 10; ++cl) se += expf(acc[cl] - mx);
        const float lse = mx + logf(se);
        #pragma unroll
        for (int cl = 0; cl < 10; ++cl)
            log_probs[(size_t)b*10 + cl] = acc[cl] - lse;
    }
}

// Symmetric 128x128-tile Gram GEMM, BK=64, conflict-free sub-chunk-major LDS.
// LDS layout per 16-row block (2048 B): [ksub j=0..7][row r=0..15][16 B];
// global_load_lds lane map: row = lane&15, j = L*4 + (lane>>4).
// Fragment read (s,quad): 256 contiguous bytes per quad-group -> 0 conflicts.
__global__ __launch_bounds__(256) void gram_kernel(
    const ushort_t* __restrict__ qn, float* __restrict__ adj)
{
    const int br = blockIdx.y, bc = blockIdx.x;
    if (br > bc) return;   // symmetry: upper-triangular block pairs only

    __shared__ ushort_t ldsA[128*64] __attribute__((aligned(16)));  // 16 KB
    __shared__ ushort_t ldsB[128*64] __attribute__((aligned(16)));  // 16 KB

    const int t = threadIdx.x;
    const int lane = t & 63, wave = t >> 6;
    const int wr = wave >> 1, wc = wave & 1;
    const int quad = lane >> 4, l16 = lane & 15;

    const int rowA0 = br * 128, rowB0 = bc * 128;

    // staging: wave handles rowblocks {2w, 2w+1}, 2 loads each (L=0,1)
    const int row_in = lane & 15;
    const int ksub   = lane >> 4;          // 0..3
    const ushort_t* gA[4]; const ushort_t* gB[4];
    ushort_t* lA[4]; ushort_t* lB[4];
    #pragma unroll
    for (int i = 0; i < 4; ++i) {
        const int rb = 2*wave + (i >> 1);
        const int L  = i & 1;
        const int kk = (L*4 + ksub) * 8;   // elem offset within 64-col tile
        gA[i] = qn + (size_t)(rowA0 + rb*16 + row_in) * K_PAD + kk;
        gB[i] = qn + (size_t)(rowB0 + rb*16 + row_in) * K_PAD + kk;
        lA[i] = &ldsA[rb*1024 + L*512];
        lB[i] = &ldsB[rb*1024 + L*512];
    }

    f32x4 acc[4][4] = {};

    for (int kt = 0; kt < N_KT; ++kt) {
        const int k0 = kt * 64;
        #pragma unroll
        for (int i = 0; i < 4; ++i) {
            __builtin_amdgcn_global_load_lds(GLOBAL_AS(gA[i] + k0), LDS_AS(lA[i]), 16, 0, 0);
            __builtin_amdgcn_global_load_lds(GLOBAL_AS(gB[i] + k0), LDS_AS(lB[i]), 16, 0, 0);
        }
        __syncthreads();

        #pragma unroll
        for (int s = 0; s < 2; ++s) {
            short8 af[4], bf[4];
            #pragma unroll
            for (int mi = 0; mi < 4; ++mi)
                af[mi] = *(const short8*)&ldsA[(wr*4 + mi)*1024 + (s*4 + quad)*128 + l16*8];
            #pragma unroll
            for (int ni = 0; ni < 4; ++ni)
                bf[ni] = *(const short8*)&ldsB[(wc*4 + ni)*1024 + (s*4 + quad)*128 + l16*8];
            #pragma unroll
            for (int mi = 0; mi < 4; ++mi)
                #pragma unroll
                for (int ni = 0; ni < 4; ++ni)
                    acc[mi][ni] = __builtin_amdgcn_mfma_f32_16x16x32_bf16(
                        af[mi], bf[ni], acc[mi][ni], 0, 0, 0);
        }
        __syncthreads();
    }

    // epilogue: fid = c^2, threshold, zero diagonal; off-diag also stores
    // the transpose as float4 over 4 consecutive rows.
    const bool offdiag = (br != bc);
    #pragma unroll
    for (int mi = 0; mi < 4; ++mi) {
        const int gr0 = br*128 + wr*64 + mi*16 + quad*4;
        #pragma unroll
        for (int ni = 0; ni < 4; ++ni) {
            const int gc = bc*128 + wc*64 + ni*16 + l16;
            const f32x4 v = acc[mi][ni];
            float o[4];
            #pragma unroll
            for (int r = 0; r < 4; ++r)
                o[r] = (v[r]*v[r] >= THRESH && (gr0 + r) != gc) ? 1.0f : 0.0f;
            #pragma unroll
            for (int r = 0; r < 4; ++r)
                adj[(size_t)(gr0 + r) * B_SZ + gc] = o[r];
            if (offdiag)
                *(float4*)&adj[(size_t)gc * B_SZ + gr0] =
                    make_float4(o[0], o[1], o[2], o[3]);
        }
    }
}

extern "C" void kernel_launch(void* const* d_in, const int* in_sizes, int n_in,
                              void* d_out, int out_size, void* d_ws, size_t ws_size,
                              hipStream_t stream) {
    const float* x       = (const float*)d_in[0];
    const float* conv_w  = (const float*)d_in[1];
    const float* conv_b  = (const float*)d_in[2];
    const float* unitary = (const float*)d_in[3];
    const float* lin_w   = (const float*)d_in[4];
    const float* lin_b   = (const float*)d_in[5];

    float* log_probs = (float*)d_out;
    float* adj       = (float*)d_out + (size_t)B_SZ * 10;
    ushort_t* qn     = (ushort_t*)d_ws;   // [8192, 832] bf16

    preproc_kernel<<<B_SZ / 4, 256, 0, stream>>>(x, conv_w, conv_b, unitary,
                                                 lin_w, lin_b, log_probs, qn);
    gram_kernel<<<dim3(64, 64), 256, 0, stream>>>(qn, adj);
}